// Round 10
// baseline (1513.485 us; speedup 1.0000x reference)
//
#include <hip/hip_runtime.h>
#include <stdint.h>

typedef __attribute__((ext_vector_type(8))) short bf16x8v;
typedef __attribute__((ext_vector_type(4))) float f32x4v;
typedef long long i64;
typedef __attribute__((ext_vector_type(2))) long long i64x2;

#define DEV static __device__ __forceinline__

#define B_   64
#define TC_  637
#define TCP_ 638
#define TT_  24
#define E_   300
#define KP_  320
#define H_   256
#define NG_  2048

DEV uint16_t f2bf(float f) {
    uint32_t u = __float_as_uint(f);
    u += 0x7fffu + ((u >> 16) & 1u);
    return (uint16_t)(u >> 16);
}
DEV float bf2f(uint16_t h) { return __uint_as_float(((uint32_t)h) << 16); }

DEV void gload_lds16(const void* g, void* l) {
    __builtin_amdgcn_global_load_lds((const __attribute__((address_space(1))) uint32_t*)g,
                                     (__attribute__((address_space(3))) uint32_t*)l, 16, 0, 0);
}

// ---------------- merged prep + gather (one launch) -------------------------
__global__ void k_pg(const float* t_wih_f, const float* t_wih_b,
                     const float* t_whh_f,
                     const float* c_wih_f, const float* c_wih_b,
                     const float* c_whh_f, const float* c_whh_b,
                     const float* t_b_f, const float* t_b_b,
                     const float* c_b_f, const float* c_b_b,
                     uint16_t* BwC, uint16_t* BwT, float* biasC, float* biasT,
                     uint32_t* w8CF, uint32_t* w8CB, uint32_t* w8TF,
                     const int* __restrict__ content, const int* __restrict__ title,
                     const float* __restrict__ emb,
                     uint16_t* __restrict__ Ac, uint16_t* __restrict__ At)
{
    if (blockIdx.x < 256) {
        int tid = blockIdx.x*blockDim.x + threadIdx.x;
        int nth = 256*256;
        for (int i = tid; i < NG_*KP_; i += nth) {
            int n = i / KP_, k = i - n*KP_;
            float vc = 0.f, vt = 0.f;
            if (k < E_) {
                vc = (n < 1024) ? c_wih_f[n*E_+k] : c_wih_b[(n-1024)*E_+k];
                vt = (n < 1024) ? t_wih_f[n*E_+k] : t_wih_b[(n-1024)*E_+k];
            }
            BwC[i] = f2bf(vc); BwT[i] = f2bf(vt);
        }
        for (int i = tid; i < 1024*H_/4; i += nth) {    // fp8 whh (all gates)
            int base = i*4;
            uint32_t a, b, c;
            a = (uint32_t)__builtin_amdgcn_cvt_pk_fp8_f32(c_whh_f[base], c_whh_f[base+1], 0, false);
            a = (uint32_t)__builtin_amdgcn_cvt_pk_fp8_f32(c_whh_f[base+2], c_whh_f[base+3], (int)a, true);
            b = (uint32_t)__builtin_amdgcn_cvt_pk_fp8_f32(c_whh_b[base], c_whh_b[base+1], 0, false);
            b = (uint32_t)__builtin_amdgcn_cvt_pk_fp8_f32(c_whh_b[base+2], c_whh_b[base+3], (int)b, true);
            c = (uint32_t)__builtin_amdgcn_cvt_pk_fp8_f32(t_whh_f[base], t_whh_f[base+1], 0, false);
            c = (uint32_t)__builtin_amdgcn_cvt_pk_fp8_f32(t_whh_f[base+2], t_whh_f[base+3], (int)c, true);
            w8CF[i] = a; w8CB[i] = b; w8TF[i] = c;
        }
        for (int i = tid; i < NG_; i += nth) {
            biasC[i] = (i < 1024) ? c_b_f[i] : c_b_b[i-1024];
            biasT[i] = (i < 1024) ? t_b_f[i] : t_b_b[i-1024];
        }
    } else {
        int tid = (blockIdx.x - 256)*blockDim.x + threadIdx.x;
        int nth = 2048*256;
        const int CCH = 40832*40;
        const int TCH = 1536*40;
        for (int i = tid; i < CCH + TCH; i += nth) {
            uint16_t* dst; int row, c8; int tok;
            if (i < CCH) {
                row = i / 40; c8 = i - row*40;
                int t = row >> 6, b = row & 63;
                tok = (t < TC_) ? content[b*TC_ + t] : -1;
                dst = Ac + (size_t)row*KP_ + c8*8;
            } else {
                int jx = i - CCH;
                row = jx / 40; c8 = jx - row*40;
                int t = row >> 6, b = row & 63;
                tok = title[b*TT_ + t];
                dst = At + (size_t)row*KP_ + c8*8;
            }
            uint32_t dd[4];
            #pragma unroll
            for (int p = 0; p < 4; ++p) {
                int k = c8*8 + p*2;
                float f0 = (tok >= 0 && k   < E_) ? emb[(size_t)tok*E_ + k]   : 0.f;
                float f1 = (tok >= 0 && k+1 < E_) ? emb[(size_t)tok*E_ + k+1] : 0.f;
                dd[p] = (uint32_t)f2bf(f0) | ((uint32_t)f2bf(f1) << 16);
            }
            uint4 q; q.x = dd[0]; q.y = dd[1]; q.z = dd[2]; q.w = dd[3];
            *(uint4*)dst = q;
        }
    }
}

// ---------------- pre-GEMM (content + title merged): D = W-tile x act^T -----
// 128x128 tile, BK=32, 4 waves, double-buffered global_load_lds staging.
// blockIdx.y < 319: content tiles; >= 319: title tiles.
__global__ __launch_bounds__(256) void k_gemm(const uint16_t* __restrict__ A,
        const uint16_t* __restrict__ Bw, const float* __restrict__ bias,
        uint16_t* __restrict__ prep,
        const uint16_t* __restrict__ A2, const uint16_t* __restrict__ Bw2,
        const float* __restrict__ bias2, uint16_t* __restrict__ prep2)
{
    __shared__ __align__(16) uint16_t lA[2][128*32];
    __shared__ __align__(16) uint16_t lB[2][128*32];
    const int tid = threadIdx.x;
    const int l = tid & 63, wv = tid >> 6;

    const uint16_t* Ax; const uint16_t* Bx; const float* bx; uint16_t* px; int m0;
    if (blockIdx.y < 319) { Ax = A;  Bx = Bw;  bx = bias;  px = prep;  m0 = blockIdx.y*128; }
    else                  { Ax = A2; Bx = Bw2; bx = bias2; px = prep2; m0 = (blockIdx.y-319)*128; }
    const int n0 = blockIdx.x * 128;

    auto stage = [&](int kc, int bi) {
        #pragma unroll
        for (int r = 0; r < 2; ++r) {
            int row = r*64 + (tid >> 2);
            int cu  = (tid & 3) * 8;
            gload_lds16(Ax + (size_t)(m0 + row)*KP_ + kc*32 + cu, &lA[bi][r*2048 + wv*512]);
            gload_lds16(Bx + (size_t)(n0 + row)*KP_ + kc*32 + cu, &lB[bi][r*2048 + wv*512]);
        }
    };

    f32x4v acc[4][4];
    #pragma unroll
    for (int i = 0; i < 4; ++i)
        #pragma unroll
        for (int j = 0; j < 4; ++j)
            acc[i][j] = f32x4v{0.f,0.f,0.f,0.f};

    const int mtb = (wv >> 1) * 4, ntb = (wv & 1) * 4;

    stage(0, 0);
    __syncthreads();
    for (int kc = 0; kc < 10; ++kc) {
        if (kc < 9) stage(kc + 1, (kc + 1) & 1);
        {
            int bi = kc & 1;
            bf16x8v af[4], bfr[4];
            #pragma unroll
            for (int i = 0; i < 4; ++i) {
                af[i]  = *(const bf16x8v*)&lA[bi][((mtb+i)*16 + (l&15))*32 + (l>>4)*8];
                bfr[i] = *(const bf16x8v*)&lB[bi][((ntb+i)*16 + (l&15))*32 + (l>>4)*8];
            }
            #pragma unroll
            for (int i = 0; i < 4; ++i)
                #pragma unroll
                for (int j = 0; j < 4; ++j)
                    acc[i][j] = __builtin_amdgcn_mfma_f32_16x16x32_bf16(bfr[j], af[i], acc[i][j], 0,0,0);
        }
        __syncthreads();
    }

    // epilogue: D[n_local = hi*4+r][m = l&15]; store ushort4 per (i,j)
    const int hi = l >> 4;
    #pragma unroll
    for (int j = 0; j < 4; ++j) {
        int n16 = (n0 >> 4) + ntb + j;      // col-tile index 0..127
        int dir = n16 >> 6;
        int q   = n16 & 63;
        int ty  = q >> 4;
        int wp  = q & 15;
        float4 bv = *(const float4*)(bx + n16*16 + hi*4);
        #pragma unroll
        for (int i = 0; i < 4; ++i) {
            int rowblk = (m0 >> 4) + mtb + i;   // 16-row block index
            int t    = rowblk >> 2;
            int bblk = rowblk & 3;
            int unit = t*8 + bblk*2 + dir;
            ushort4 pk;
            pk.x = f2bf(acc[i][j][0] + bv.x);
            pk.y = f2bf(acc[i][j][1] + bv.y);
            pk.z = f2bf(acc[i][j][2] + bv.z);
            pk.w = f2bf(acc[i][j][3] + bv.w);
            size_t off = (size_t)unit*16384 + (size_t)wp*1024 + (size_t)l*16 + ty*4;
            *(ushort4*)(px + off) = pk;
        }
    }
}

// MFMA asm helper (weights pinned in AGPRs)
#define MF(ACC, W, AA) asm("v_mfma_f32_16x16x32_fp8_fp8 %0, %1, %2, %0" \
                           : "+v"(ACC) : "a"(W), "v"(AA))

// ---------------- recurrence: one block per (direction, 16-batch) unit ------
// 16 waves x 64 lanes; weights in 64 AGPRs (asm-pinned). h: fp8, 2x4KB LDS,
// kc-pair subtiled, conflict-free b128 reads. R5-proven structure (rotation-
// ordered MFMA chains, top prefetch, one lgkm-only barrier/step) + setprio
// around the MFMA cluster. Register fit: 60 VGPR + 64 AGPR = 124/128 at
// 4 waves/SIMD -- do not add register pressure (R8 lesson).
__global__ __launch_bounds__(1024, 4) void k_rnn(
    const uint16_t* __restrict__ preC, const uint16_t* __restrict__ preT,
    const uint8_t* __restrict__ w8CF, const uint8_t* __restrict__ w8CB,
    const uint8_t* __restrict__ w8TF,
    uint16_t* __restrict__ cr, float* __restrict__ tl)
{
    __shared__ __align__(16) char smem[8192];   // 2 x 4KB fp8-h buffers

    const int tid = threadIdx.x;
    const int l = tid & 63, wp = tid >> 6;      // wp 0..15
    const int m = l & 15, hi = l >> 4;
    const int u = blockIdx.x;

    int dir, bblk, t0, tstep, nsteps, tlOff = -1;
    bool doCR = false;
    const uint16_t* pre; const uint8_t* whh8 = nullptr;
    if (u < 8) {
        dir = u & 1; bblk = u >> 1;
        nsteps = TC_; t0 = dir ? (TC_-1) : 0; tstep = dir ? -1 : 1;
        whh8 = dir ? w8CB : w8CF; pre = preC; doCR = true;
    } else if (u < 12) {
        dir = 0; bblk = u - 8; nsteps = TT_; t0 = 0; tstep = 1;
        whh8 = w8TF; pre = preT; tlOff = 0;
    } else {
        dir = 1; bblk = u - 12; nsteps = 1; t0 = TT_-1; tstep = -1;
        whh8 = nullptr; pre = preT; tlOff = 256;
    }
    const int b0 = bblk * 16;

    // ---- weights: 4 fp8 tiles {i,f,g,o} for this wave's 16 h-cols ----------
    i64 w8r[4][8];
    if (whh8) {
        #pragma unroll
        for (int ty = 0; ty < 4; ++ty) {
            int n = ty*256 + wp*16 + m;
            #pragma unroll
            for (int kc = 0; kc < 8; ++kc)
                w8r[ty][kc] = *(const i64*)(whh8 + (size_t)n*H_ + kc*32 + hi*8);
        }
        #pragma unroll
        for (int ty = 0; ty < 4; ++ty)
            #pragma unroll
            for (int kc = 0; kc < 8; ++kc)
                asm volatile("" : "+a"(w8r[ty][kc]));
    }
    for (int i = tid; i < 2048; i += 1024) ((uint32_t*)smem)[i] = 0;
    __syncthreads();

    // ---- per-lane constants ------------------------------------------------
    int rda[4];
    #pragma unroll
    for (int q = 0; q < 4; ++q) rda[q] = m*256 + hi*64 + (((q ^ (m & 3))) << 4);
    const int waddr = m*256 + (((wp*2 + (hi >> 1)) & 3) << 6)
                    + ((((wp >> 2) ^ (m & 3))) << 4)
                    + (((wp >> 1) & 1) << 3) + ((hi & 1) << 2);

    uint16_t* crp = cr + ((size_t)(b0 + m)*TC_ + t0)*512 + dir*256 + (wp << 4) + hi*4;
    const intptr_t crAdv = (intptr_t)tstep * 512;

    float cst[4] = {0.f, 0.f, 0.f, 0.f};

    const uint16_t* pp = pre + (size_t)(t0*8 + bblk*2 + dir)*16384
                             + (size_t)(wp << 10) + (size_t)l*16;
    const intptr_t ppAdv = (intptr_t)tstep * 131072;

    uint4 pf0 = *(const uint4*)(pp);
    uint4 pf1 = *(const uint4*)(pp + 8);

    const float KN = -1.4426950408889634f;      // -log2(e)
    const float K2 =  2.8853900817779268f;      //  2 log2(e)

    for (int s = 0; s < nsteps; ++s) {
        const char* hb = (const char*)smem + (s & 1)*4096;
        char*       ho = smem + ((s & 1) ^ 1)*4096;

        // decode pre -> acc (bf16 in hi-half trick)
        f32x4v acc[4];
        acc[0][0]=__uint_as_float(pf0.x<<16); acc[0][1]=__uint_as_float(pf0.x&0xffff0000u);
        acc[0][2]=__uint_as_float(pf0.y<<16); acc[0][3]=__uint_as_float(pf0.y&0xffff0000u);
        acc[1][0]=__uint_as_float(pf0.z<<16); acc[1][1]=__uint_as_float(pf0.z&0xffff0000u);
        acc[1][2]=__uint_as_float(pf0.w<<16); acc[1][3]=__uint_as_float(pf0.w&0xffff0000u);
        acc[2][0]=__uint_as_float(pf1.x<<16); acc[2][1]=__uint_as_float(pf1.x&0xffff0000u);
        acc[2][2]=__uint_as_float(pf1.y<<16); acc[2][3]=__uint_as_float(pf1.y&0xffff0000u);
        acc[3][0]=__uint_as_float(pf1.z<<16); acc[3][1]=__uint_as_float(pf1.z&0xffff0000u);
        acc[3][2]=__uint_as_float(pf1.w<<16); acc[3][3]=__uint_as_float(pf1.w&0xffff0000u);

        // prefetch next step's pre (issued at step top; full-step latency window)
        if (s + 1 < nsteps) {
            pp += ppAdv;
            pf0 = *(const uint4*)(pp);
            pf1 = *(const uint4*)(pp + 8);
        }

        if (whh8) {
            __builtin_amdgcn_s_setprio(1);
            #pragma unroll
            for (int q = 0; q < 4; ++q) {
                i64x2 a = *(const i64x2*)(hb + rda[q]);
                MF(acc[0], w8r[0][2*q], a[0]);
                MF(acc[1], w8r[1][2*q], a[0]);
                MF(acc[2], w8r[2][2*q], a[0]);
                MF(acc[3], w8r[3][2*q], a[0]);
                MF(acc[0], w8r[0][2*q+1], a[1]);
                MF(acc[1], w8r[1][2*q+1], a[1]);
                MF(acc[2], w8r[2][2*q+1], a[1]);
                MF(acc[3], w8r[3][2*q+1], a[1]);
            }
            __builtin_amdgcn_s_setprio(0);
        }

        // nonlinearity: common-denominator form (5 exp + 2 rcp per output)
        float hv[4];
        #pragma unroll
        for (int r = 0; r < 4; ++r) {
            float Ei = __builtin_amdgcn_exp2f(acc[0][r] * KN);
            float Ef = __builtin_amdgcn_exp2f(acc[1][r] * KN);
            float Eg = __builtin_amdgcn_exp2f(acc[2][r] * (2.f*KN));
            float Eo = __builtin_amdgcn_exp2f(acc[3][r] * KN);
            float A  = 1.f + Ei;
            float Bb = 1.f + Eg;
            float C  = 1.f + Ef;
            float AB = A * Bb;
            float num = __builtin_fmaf(cst[r], AB, (2.f - Bb) * C);
            float cv  = num * __builtin_amdgcn_rcpf(AB * C);
            cst[r] = cv;
            float cc = fminf(fmaxf(cv, -15.f), 15.f);
            float P  = __builtin_amdgcn_exp2f(cc * K2);
            hv[r] = (P - 1.f) * __builtin_amdgcn_rcpf((1.f + Eo) * (P + 1.f));
        }

        uint32_t p8 = (uint32_t)__builtin_amdgcn_cvt_pk_fp8_f32(hv[0], hv[1], 0, false);
        p8 = (uint32_t)__builtin_amdgcn_cvt_pk_fp8_f32(hv[2], hv[3], (int)p8, true);
        *(uint32_t*)(ho + waddr) = p8;

        if (doCR) {
            uint32_t b01, b23;
            asm("v_cvt_pk_bf16_f32 %0, %1, %2" : "=v"(b01) : "v"(hv[0]), "v"(hv[1]));
            asm("v_cvt_pk_bf16_f32 %0, %1, %2" : "=v"(b23) : "v"(hv[2]), "v"(hv[3]));
            uint2 st; st.x = b01; st.y = b23;
            *(uint2*)crp = st;
            crp += crAdv;
        }
        if (tlOff >= 0 && s == nsteps - 1) {
            float4 fv; fv.x = hv[0]; fv.y = hv[1]; fv.z = hv[2]; fv.w = hv[3];
            *(float4*)(tl + (size_t)(b0 + m)*512 + tlOff + (wp << 4) + hi*4) = fv;
        }

        // one barrier per step: LDS-only drain; global ops stay in flight
        __builtin_amdgcn_sched_barrier(0);
        asm volatile("s_waitcnt lgkmcnt(0)" ::: "memory");
        __builtin_amdgcn_s_barrier();
        __builtin_amdgcn_sched_barrier(0);
    }
}

// ---------------- attention + fc + log_softmax, one block per batch --------
// Score loop: wave-per-t, lane-per-column (coalesced 1KB row reads) with
// hoisted per-lane sQ registers + shfl_xor wave reduce (was: per-thread full
// row reads, 1KB lane stride, fully uncoalesced).
__global__ __launch_bounds__(256) void k_attn(const uint16_t* __restrict__ cr,
        const float* __restrict__ tl, const float* __restrict__ attw,
        const float* __restrict__ fcw, const float* __restrict__ fcb,
        float* __restrict__ out)
{
    __shared__ float sT[512];
    __shared__ float sQ[512];
    __shared__ float sS[640];
    __shared__ float sR[256];
    const int b = blockIdx.x, tid = threadIdx.x;
    const int l = tid & 63, wv = tid >> 6;
    for (int i = tid; i < 512; i += 256) sT[i] = tl[(size_t)b*512 + i];
    __syncthreads();
    for (int n = tid; n < 512; n += 256) {
        float s = 0.f;
        for (int j = 0; j < 512; ++j) s += sT[j] * attw[(size_t)j*512 + n];
        sQ[n] = s;
    }
    __syncthreads();
    // hoist this lane's 8 sQ values (cols l*8 .. l*8+7); conflict cost paid once
    float q0 = sQ[l*8+0], q1 = sQ[l*8+1], q2 = sQ[l*8+2], q3 = sQ[l*8+3];
    float q4 = sQ[l*8+4], q5 = sQ[l*8+5], q6 = sQ[l*8+6], q7 = sQ[l*8+7];
    for (int t = wv; t < TC_; t += 4) {
        uint4 v = *(const uint4*)(cr + ((size_t)b*TC_ + t)*512 + l*8);
        float s;
        s  = bf2f((uint16_t)(v.x&0xffff))*q0 + bf2f((uint16_t)(v.x>>16))*q1;
        s += bf2f((uint16_t)(v.y&0xffff))*q2 + bf2f((uint16_t)(v.y>>16))*q3;
        s += bf2f((uint16_t)(v.z&0xffff))*q4 + bf2f((uint16_t)(v.z>>16))*q5;
        s += bf2f((uint16_t)(v.w&0xffff))*q6 + bf2f((uint16_t)(v.w>>16))*q7;
        #pragma unroll
        for (int o = 1; o < 64; o <<= 1) s += __shfl_xor(s, o);
        if (l == 0) sS[t] = s;
    }
    __syncthreads();
    float lm = -1e30f;
    for (int t = tid; t < TC_; t += 256) lm = fmaxf(lm, sS[t]);
    sR[tid] = lm; __syncthreads();
    for (int o = 128; o > 0; o >>= 1) { if (tid < o) sR[tid] = fmaxf(sR[tid], sR[tid+o]); __syncthreads(); }
    float M = sR[0]; __syncthreads();
    float ls = 0.f;
    for (int t = tid; t < TC_; t += 256) { float e = __expf(sS[t]-M); sS[t] = e; ls += e; }
    sR[tid] = ls; __syncthreads();
    for (int o = 128; o > 0; o >>= 1) { if (tid < o) sR[tid] += sR[tid+o]; __syncthreads(); }
    float inv = 1.f / sR[0]; __syncthreads();
    float la[5] = {0.f,0.f,0.f,0.f,0.f};
    for (int t = tid; t < TC_; t += 256) {
        float p = sS[t] * inv;
        #pragma unroll
        for (int ll = 0; ll < 5; ++ll) la[ll] += p * fcw[ll*TC_ + t];
    }
    float lg[5];
    #pragma unroll
    for (int ll = 0; ll < 5; ++ll) {
        sR[tid] = la[ll]; __syncthreads();
        for (int o = 128; o > 0; o >>= 1) { if (tid < o) sR[tid] += sR[tid+o]; __syncthreads(); }
        lg[ll] = sR[0] + fcb[ll]; __syncthreads();
    }
    if (tid == 0) {
        float m2 = lg[0];
        #pragma unroll
        for (int ll = 1; ll < 5; ++ll) m2 = fmaxf(m2, lg[ll]);
        float se = 0.f;
        #pragma unroll
        for (int ll = 0; ll < 5; ++ll) se += __expf(lg[ll] - m2);
        float lse = __logf(se) + m2;
        #pragma unroll
        for (int ll = 0; ll < 5; ++ll) out[b*5 + ll] = lg[ll] - lse;
    }
}

// ---------------------------------------------------------------------------
extern "C" void kernel_launch(void* const* d_in, const int* in_sizes, int n_in,
                              void* d_out, int out_size, void* d_ws, size_t ws_size,
                              hipStream_t stream)
{
    const int*   content = (const int*)d_in[0];
    const int*   title   = (const int*)d_in[1];
    const float* embed_w = (const float*)d_in[2];
    const float* t_wih_f = (const float*)d_in[3];
    const float* t_whh_f = (const float*)d_in[4];
    const float* t_b_f   = (const float*)d_in[5];
    const float* t_wih_b = (const float*)d_in[6];
    const float* t_b_b   = (const float*)d_in[8];
    const float* c_wih_f = (const float*)d_in[9];
    const float* c_whh_f = (const float*)d_in[10];
    const float* c_b_f   = (const float*)d_in[11];
    const float* c_wih_b = (const float*)d_in[12];
    const float* c_whh_b = (const float*)d_in[13];
    const float* c_b_b   = (const float*)d_in[14];
    const float* att_w   = (const float*)d_in[15];
    const float* fc_w    = (const float*)d_in[16];
    const float* fc_b    = (const float*)d_in[17];
    float* out = (float*)d_out;

    char* ws = (char*)d_ws;
    size_t o = 0;
    auto alloc = [&](size_t sz) { char* p = ws + o; o = (o + sz + 255) & ~(size_t)255; return p; };
    uint16_t* Ac    = (uint16_t*)alloc((size_t)40832*KP_*2);
    uint16_t* At    = (uint16_t*)alloc((size_t)1536*KP_*2);
    uint16_t* BwC   = (uint16_t*)alloc((size_t)NG_*KP_*2);
    uint16_t* BwT   = (uint16_t*)alloc((size_t)NG_*KP_*2);
    float*    biasC = (float*)   alloc((size_t)NG_*4);
    float*    biasT = (float*)   alloc((size_t)NG_*4);
    uint8_t*  w8CF  = (uint8_t*) alloc((size_t)1024*H_);
    uint8_t*  w8CB  = (uint8_t*) alloc((size_t)1024*H_);
    uint8_t*  w8TF  = (uint8_t*) alloc((size_t)1024*H_);
    uint16_t* preC  = (uint16_t*)alloc((size_t)TCP_*262144);
    uint16_t* preT  = (uint16_t*)alloc((size_t)TT_*262144);
    uint16_t* crp   = (uint16_t*)alloc((size_t)B_*TC_*512*2);
    float*    tlp   = (float*)   alloc((size_t)B_*512*4);

    k_pg<<<2304, 256, 0, stream>>>(t_wih_f, t_wih_b, t_whh_f, c_wih_f, c_wih_b,
                                   c_whh_f, c_whh_b, t_b_f, t_b_b, c_b_f, c_b_b,
                                   BwC, BwT, biasC, biasT,
                                   (uint32_t*)w8CF, (uint32_t*)w8CB, (uint32_t*)w8TF,
                                   content, title, embed_w, Ac, At);
    k_gemm<<<dim3(16, 331), 256, 0, stream>>>(Ac, BwC, biasC, preC,
                                              At, BwT, biasT, preT);
    k_rnn<<<16, 1024, 0, stream>>>(preC, preT, w8CF, w8CB, w8TF, crp, tlp);
    k_attn<<<64, 256, 0, stream>>>(crp, tlp, att_w, fc_w, fc_b, out);
}

// Round 11
// 1453.038 us; speedup vs baseline: 1.0416x; 1.0416x over previous
//
#include <hip/hip_runtime.h>
#include <stdint.h>

typedef __attribute__((ext_vector_type(8))) short bf16x8v;
typedef __attribute__((ext_vector_type(4))) float f32x4v;
typedef long long i64;
typedef __attribute__((ext_vector_type(2))) long long i64x2;

#define DEV static __device__ __forceinline__

#define B_   64
#define TC_  637
#define TCP_ 638
#define TT_  24
#define E_   300
#define KP_  320
#define H_   256
#define NG_  2048

DEV uint16_t f2bf(float f) {
    uint32_t u = __float_as_uint(f);
    u += 0x7fffu + ((u >> 16) & 1u);
    return (uint16_t)(u >> 16);
}
DEV float bf2f(uint16_t h) { return __uint_as_float(((uint32_t)h) << 16); }

DEV void gload_lds16(const void* g, void* l) {
    __builtin_amdgcn_global_load_lds((const __attribute__((address_space(1))) uint32_t*)g,
                                     (__attribute__((address_space(3))) uint32_t*)l, 16, 0, 0);
}

// ---------------- merged prep + gather (one launch) -------------------------
__global__ void k_pg(const float* t_wih_f, const float* t_wih_b,
                     const float* t_whh_f,
                     const float* c_wih_f, const float* c_wih_b,
                     const float* c_whh_f, const float* c_whh_b,
                     const float* t_b_f, const float* t_b_b,
                     const float* c_b_f, const float* c_b_b,
                     uint16_t* BwC, uint16_t* BwT, float* biasC, float* biasT,
                     uint32_t* w8CF, uint32_t* w8CB, uint32_t* w8TF,
                     const int* __restrict__ content, const int* __restrict__ title,
                     const float* __restrict__ emb,
                     uint16_t* __restrict__ Ac, uint16_t* __restrict__ At)
{
    if (blockIdx.x < 256) {
        int tid = blockIdx.x*blockDim.x + threadIdx.x;
        int nth = 256*256;
        for (int i = tid; i < NG_*KP_; i += nth) {
            int n = i / KP_, k = i - n*KP_;
            float vc = 0.f, vt = 0.f;
            if (k < E_) {
                vc = (n < 1024) ? c_wih_f[n*E_+k] : c_wih_b[(n-1024)*E_+k];
                vt = (n < 1024) ? t_wih_f[n*E_+k] : t_wih_b[(n-1024)*E_+k];
            }
            BwC[i] = f2bf(vc); BwT[i] = f2bf(vt);
        }
        for (int i = tid; i < 1024*H_/4; i += nth) {    // fp8 whh (all gates)
            int base = i*4;
            uint32_t a, b, c;
            a = (uint32_t)__builtin_amdgcn_cvt_pk_fp8_f32(c_whh_f[base], c_whh_f[base+1], 0, false);
            a = (uint32_t)__builtin_amdgcn_cvt_pk_fp8_f32(c_whh_f[base+2], c_whh_f[base+3], (int)a, true);
            b = (uint32_t)__builtin_amdgcn_cvt_pk_fp8_f32(c_whh_b[base], c_whh_b[base+1], 0, false);
            b = (uint32_t)__builtin_amdgcn_cvt_pk_fp8_f32(c_whh_b[base+2], c_whh_b[base+3], (int)b, true);
            c = (uint32_t)__builtin_amdgcn_cvt_pk_fp8_f32(t_whh_f[base], t_whh_f[base+1], 0, false);
            c = (uint32_t)__builtin_amdgcn_cvt_pk_fp8_f32(t_whh_f[base+2], t_whh_f[base+3], (int)c, true);
            w8CF[i] = a; w8CB[i] = b; w8TF[i] = c;
        }
        for (int i = tid; i < NG_; i += nth) {
            biasC[i] = (i < 1024) ? c_b_f[i] : c_b_b[i-1024];
            biasT[i] = (i < 1024) ? t_b_f[i] : t_b_b[i-1024];
        }
    } else {
        int tid = (blockIdx.x - 256)*blockDim.x + threadIdx.x;
        int nth = 2048*256;
        const int CCH = 40832*40;
        const int TCH = 1536*40;
        for (int i = tid; i < CCH + TCH; i += nth) {
            uint16_t* dst; int row, c8; int tok;
            if (i < CCH) {
                row = i / 40; c8 = i - row*40;
                int t = row >> 6, b = row & 63;
                tok = (t < TC_) ? content[b*TC_ + t] : -1;
                dst = Ac + (size_t)row*KP_ + c8*8;
            } else {
                int jx = i - CCH;
                row = jx / 40; c8 = jx - row*40;
                int t = row >> 6, b = row & 63;
                tok = title[b*TT_ + t];
                dst = At + (size_t)row*KP_ + c8*8;
            }
            uint32_t dd[4];
            #pragma unroll
            for (int p = 0; p < 4; ++p) {
                int k = c8*8 + p*2;
                float f0 = (tok >= 0 && k   < E_) ? emb[(size_t)tok*E_ + k]   : 0.f;
                float f1 = (tok >= 0 && k+1 < E_) ? emb[(size_t)tok*E_ + k+1] : 0.f;
                dd[p] = (uint32_t)f2bf(f0) | ((uint32_t)f2bf(f1) << 16);
            }
            uint4 q; q.x = dd[0]; q.y = dd[1]; q.z = dd[2]; q.w = dd[3];
            *(uint4*)dst = q;
        }
    }
}

// ---------------- pre-GEMM (content + title merged): D = W-tile x act^T -----
// 128x128 tile, BK=32, 4 waves, double-buffered global_load_lds staging.
// blockIdx.y < 319: content tiles; >= 319: title tiles.
__global__ __launch_bounds__(256) void k_gemm(const uint16_t* __restrict__ A,
        const uint16_t* __restrict__ Bw, const float* __restrict__ bias,
        uint16_t* __restrict__ prep,
        const uint16_t* __restrict__ A2, const uint16_t* __restrict__ Bw2,
        const float* __restrict__ bias2, uint16_t* __restrict__ prep2)
{
    __shared__ __align__(16) uint16_t lA[2][128*32];
    __shared__ __align__(16) uint16_t lB[2][128*32];
    const int tid = threadIdx.x;
    const int l = tid & 63, wv = tid >> 6;

    const uint16_t* Ax; const uint16_t* Bx; const float* bx; uint16_t* px; int m0;
    if (blockIdx.y < 319) { Ax = A;  Bx = Bw;  bx = bias;  px = prep;  m0 = blockIdx.y*128; }
    else                  { Ax = A2; Bx = Bw2; bx = bias2; px = prep2; m0 = (blockIdx.y-319)*128; }
    const int n0 = blockIdx.x * 128;

    auto stage = [&](int kc, int bi) {
        #pragma unroll
        for (int r = 0; r < 2; ++r) {
            int row = r*64 + (tid >> 2);
            int cu  = (tid & 3) * 8;
            gload_lds16(Ax + (size_t)(m0 + row)*KP_ + kc*32 + cu, &lA[bi][r*2048 + wv*512]);
            gload_lds16(Bx + (size_t)(n0 + row)*KP_ + kc*32 + cu, &lB[bi][r*2048 + wv*512]);
        }
    };

    f32x4v acc[4][4];
    #pragma unroll
    for (int i = 0; i < 4; ++i)
        #pragma unroll
        for (int j = 0; j < 4; ++j)
            acc[i][j] = f32x4v{0.f,0.f,0.f,0.f};

    const int mtb = (wv >> 1) * 4, ntb = (wv & 1) * 4;

    stage(0, 0);
    __syncthreads();
    for (int kc = 0; kc < 10; ++kc) {
        if (kc < 9) stage(kc + 1, (kc + 1) & 1);
        {
            int bi = kc & 1;
            bf16x8v af[4], bfr[4];
            #pragma unroll
            for (int i = 0; i < 4; ++i) {
                af[i]  = *(const bf16x8v*)&lA[bi][((mtb+i)*16 + (l&15))*32 + (l>>4)*8];
                bfr[i] = *(const bf16x8v*)&lB[bi][((ntb+i)*16 + (l&15))*32 + (l>>4)*8];
            }
            #pragma unroll
            for (int i = 0; i < 4; ++i)
                #pragma unroll
                for (int j = 0; j < 4; ++j)
                    acc[i][j] = __builtin_amdgcn_mfma_f32_16x16x32_bf16(bfr[j], af[i], acc[i][j], 0,0,0);
        }
        __syncthreads();
    }

    // epilogue: D[n_local = hi*4+r][m = l&15]; store ushort4 per (i,j)
    const int hi = l >> 4;
    #pragma unroll
    for (int j = 0; j < 4; ++j) {
        int n16 = (n0 >> 4) + ntb + j;      // col-tile index 0..127
        int dir = n16 >> 6;
        int q   = n16 & 63;
        int ty  = q >> 4;
        int wp  = q & 15;
        float4 bv = *(const float4*)(bx + n16*16 + hi*4);
        #pragma unroll
        for (int i = 0; i < 4; ++i) {
            int rowblk = (m0 >> 4) + mtb + i;   // 16-row block index
            int t    = rowblk >> 2;
            int bblk = rowblk & 3;
            int unit = t*8 + bblk*2 + dir;
            ushort4 pk;
            pk.x = f2bf(acc[i][j][0] + bv.x);
            pk.y = f2bf(acc[i][j][1] + bv.y);
            pk.z = f2bf(acc[i][j][2] + bv.z);
            pk.w = f2bf(acc[i][j][3] + bv.w);
            size_t off = (size_t)unit*16384 + (size_t)wp*1024 + (size_t)l*16 + ty*4;
            *(ushort4*)(px + off) = pk;
        }
    }
}

// MFMA asm helper (weights pinned in AGPRs)
#define MF(ACC, W, AA) asm("v_mfma_f32_16x16x32_fp8_fp8 %0, %1, %2, %0" \
                           : "+v"(ACC) : "a"(W), "v"(AA))

// ---------------- recurrence: one block per (direction, 16-batch) unit ------
// 16 waves x 64 lanes; weights in 64 AGPRs (asm-pinned). h: fp8, 2x4KB LDS,
// kc-pair subtiled, conflict-free b128 reads. R5-proven structure (rotation-
// ordered MFMA chains, top prefetch, one lgkm-only barrier/step) + setprio
// around the MFMA cluster. Register fit: 60 VGPR + 64 AGPR = 124/128 at
// 4 waves/SIMD -- do not add register pressure (R8 lesson).
__global__ __launch_bounds__(1024, 4) void k_rnn(
    const uint16_t* __restrict__ preC, const uint16_t* __restrict__ preT,
    const uint8_t* __restrict__ w8CF, const uint8_t* __restrict__ w8CB,
    const uint8_t* __restrict__ w8TF,
    uint16_t* __restrict__ cr, float* __restrict__ tl)
{
    __shared__ __align__(16) char smem[8192];   // 2 x 4KB fp8-h buffers

    const int tid = threadIdx.x;
    const int l = tid & 63, wp = tid >> 6;      // wp 0..15
    const int m = l & 15, hi = l >> 4;
    const int u = blockIdx.x;

    int dir, bblk, t0, tstep, nsteps, tlOff = -1;
    bool doCR = false;
    const uint16_t* pre; const uint8_t* whh8 = nullptr;
    if (u < 8) {
        dir = u & 1; bblk = u >> 1;
        nsteps = TC_; t0 = dir ? (TC_-1) : 0; tstep = dir ? -1 : 1;
        whh8 = dir ? w8CB : w8CF; pre = preC; doCR = true;
    } else if (u < 12) {
        dir = 0; bblk = u - 8; nsteps = TT_; t0 = 0; tstep = 1;
        whh8 = w8TF; pre = preT; tlOff = 0;
    } else {
        dir = 1; bblk = u - 12; nsteps = 1; t0 = TT_-1; tstep = -1;
        whh8 = nullptr; pre = preT; tlOff = 256;
    }
    const int b0 = bblk * 16;

    // ---- weights: 4 fp8 tiles {i,f,g,o} for this wave's 16 h-cols ----------
    i64 w8r[4][8];
    if (whh8) {
        #pragma unroll
        for (int ty = 0; ty < 4; ++ty) {
            int n = ty*256 + wp*16 + m;
            #pragma unroll
            for (int kc = 0; kc < 8; ++kc)
                w8r[ty][kc] = *(const i64*)(whh8 + (size_t)n*H_ + kc*32 + hi*8);
        }
        #pragma unroll
        for (int ty = 0; ty < 4; ++ty)
            #pragma unroll
            for (int kc = 0; kc < 8; ++kc)
                asm volatile("" : "+a"(w8r[ty][kc]));
    }
    for (int i = tid; i < 2048; i += 1024) ((uint32_t*)smem)[i] = 0;
    __syncthreads();

    // ---- per-lane constants ------------------------------------------------
    int rda[4];
    #pragma unroll
    for (int q = 0; q < 4; ++q) rda[q] = m*256 + hi*64 + (((q ^ (m & 3))) << 4);
    const int waddr = m*256 + (((wp*2 + (hi >> 1)) & 3) << 6)
                    + ((((wp >> 2) ^ (m & 3))) << 4)
                    + (((wp >> 1) & 1) << 3) + ((hi & 1) << 2);

    uint16_t* crp = cr + ((size_t)(b0 + m)*TC_ + t0)*512 + dir*256 + (wp << 4) + hi*4;
    const intptr_t crAdv = (intptr_t)tstep * 512;

    float cst[4] = {0.f, 0.f, 0.f, 0.f};

    const uint16_t* pp = pre + (size_t)(t0*8 + bblk*2 + dir)*16384
                             + (size_t)(wp << 10) + (size_t)l*16;
    const intptr_t ppAdv = (intptr_t)tstep * 131072;

    uint4 pf0 = *(const uint4*)(pp);
    uint4 pf1 = *(const uint4*)(pp + 8);

    const float KN = -1.4426950408889634f;      // -log2(e)
    const float K2 =  2.8853900817779268f;      //  2 log2(e)

    for (int s = 0; s < nsteps; ++s) {
        const char* hb = (const char*)smem + (s & 1)*4096;
        char*       ho = smem + ((s & 1) ^ 1)*4096;

        // decode pre -> acc (bf16 in hi-half trick)
        f32x4v acc[4];
        acc[0][0]=__uint_as_float(pf0.x<<16); acc[0][1]=__uint_as_float(pf0.x&0xffff0000u);
        acc[0][2]=__uint_as_float(pf0.y<<16); acc[0][3]=__uint_as_float(pf0.y&0xffff0000u);
        acc[1][0]=__uint_as_float(pf0.z<<16); acc[1][1]=__uint_as_float(pf0.z&0xffff0000u);
        acc[1][2]=__uint_as_float(pf0.w<<16); acc[1][3]=__uint_as_float(pf0.w&0xffff0000u);
        acc[2][0]=__uint_as_float(pf1.x<<16); acc[2][1]=__uint_as_float(pf1.x&0xffff0000u);
        acc[2][2]=__uint_as_float(pf1.y<<16); acc[2][3]=__uint_as_float(pf1.y&0xffff0000u);
        acc[3][0]=__uint_as_float(pf1.z<<16); acc[3][1]=__uint_as_float(pf1.z&0xffff0000u);
        acc[3][2]=__uint_as_float(pf1.w<<16); acc[3][3]=__uint_as_float(pf1.w&0xffff0000u);

        // prefetch next step's pre (issued at step top; full-step latency window)
        if (s + 1 < nsteps) {
            pp += ppAdv;
            pf0 = *(const uint4*)(pp);
            pf1 = *(const uint4*)(pp + 8);
        }

        if (whh8) {
            __builtin_amdgcn_s_setprio(1);
            #pragma unroll
            for (int q = 0; q < 4; ++q) {
                i64x2 a = *(const i64x2*)(hb + rda[q]);
                MF(acc[0], w8r[0][2*q], a[0]);
                MF(acc[1], w8r[1][2*q], a[0]);
                MF(acc[2], w8r[2][2*q], a[0]);
                MF(acc[3], w8r[3][2*q], a[0]);
                MF(acc[0], w8r[0][2*q+1], a[1]);
                MF(acc[1], w8r[1][2*q+1], a[1]);
                MF(acc[2], w8r[2][2*q+1], a[1]);
                MF(acc[3], w8r[3][2*q+1], a[1]);
            }
            __builtin_amdgcn_s_setprio(0);
        }

        // nonlinearity: common-denominator form (5 exp + 2 rcp per output)
        float hv[4];
        #pragma unroll
        for (int r = 0; r < 4; ++r) {
            float Ei = __builtin_amdgcn_exp2f(acc[0][r] * KN);
            float Ef = __builtin_amdgcn_exp2f(acc[1][r] * KN);
            float Eg = __builtin_amdgcn_exp2f(acc[2][r] * (2.f*KN));
            float Eo = __builtin_amdgcn_exp2f(acc[3][r] * KN);
            float A  = 1.f + Ei;
            float Bb = 1.f + Eg;
            float C  = 1.f + Ef;
            float AB = A * Bb;
            float num = __builtin_fmaf(cst[r], AB, (2.f - Bb) * C);
            float cv  = num * __builtin_amdgcn_rcpf(AB * C);
            cst[r] = cv;
            float cc = fminf(fmaxf(cv, -15.f), 15.f);
            float P  = __builtin_amdgcn_exp2f(cc * K2);
            hv[r] = (P - 1.f) * __builtin_amdgcn_rcpf((1.f + Eo) * (P + 1.f));
        }

        uint32_t p8 = (uint32_t)__builtin_amdgcn_cvt_pk_fp8_f32(hv[0], hv[1], 0, false);
        p8 = (uint32_t)__builtin_amdgcn_cvt_pk_fp8_f32(hv[2], hv[3], (int)p8, true);
        *(uint32_t*)(ho + waddr) = p8;

        if (doCR) {
            uint32_t b01, b23;
            asm("v_cvt_pk_bf16_f32 %0, %1, %2" : "=v"(b01) : "v"(hv[0]), "v"(hv[1]));
            asm("v_cvt_pk_bf16_f32 %0, %1, %2" : "=v"(b23) : "v"(hv[2]), "v"(hv[3]));
            uint2 st; st.x = b01; st.y = b23;
            *(uint2*)crp = st;
            crp += crAdv;
        }
        if (tlOff >= 0 && s == nsteps - 1) {
            float4 fv; fv.x = hv[0]; fv.y = hv[1]; fv.z = hv[2]; fv.w = hv[3];
            *(float4*)(tl + (size_t)(b0 + m)*512 + tlOff + (wp << 4) + hi*4) = fv;
        }

        // one barrier per step: LDS-only drain; global ops stay in flight
        __builtin_amdgcn_sched_barrier(0);
        asm volatile("s_waitcnt lgkmcnt(0)" ::: "memory");
        __builtin_amdgcn_s_barrier();
        __builtin_amdgcn_sched_barrier(0);
    }
}

// ---------------- attention + fc + log_softmax, one block per batch --------
// (R9-proven version: per-thread row dots; cr is L2/L3-resident so the
// scattered reads are cache-absorbed -- the R10 wave-reduce rewrite
// regressed and was reverted.)
__global__ __launch_bounds__(256) void k_attn(const uint16_t* __restrict__ cr,
        const float* __restrict__ tl, const float* __restrict__ attw,
        const float* __restrict__ fcw, const float* __restrict__ fcb,
        float* __restrict__ out)
{
    __shared__ float sT[512];
    __shared__ float sQ[512];
    __shared__ float sS[640];
    __shared__ float sR[256];
    const int b = blockIdx.x, tid = threadIdx.x;
    for (int i = tid; i < 512; i += 256) sT[i] = tl[(size_t)b*512 + i];
    __syncthreads();
    for (int n = tid; n < 512; n += 256) {
        float s = 0.f;
        for (int j = 0; j < 512; ++j) s += sT[j] * attw[(size_t)j*512 + n];
        sQ[n] = s;
    }
    __syncthreads();
    for (int t = tid; t < TC_; t += 256) {
        const uint16_t* row = cr + ((size_t)b*TC_ + t)*512;
        float s = 0.f;
        for (int c = 0; c < 64; ++c) {
            uint4 v = *(const uint4*)(row + c*8);
            uint32_t d;
            d = v.x; s += bf2f((uint16_t)(d&0xffff))*sQ[c*8+0] + bf2f((uint16_t)(d>>16))*sQ[c*8+1];
            d = v.y; s += bf2f((uint16_t)(d&0xffff))*sQ[c*8+2] + bf2f((uint16_t)(d>>16))*sQ[c*8+3];
            d = v.z; s += bf2f((uint16_t)(d&0xffff))*sQ[c*8+4] + bf2f((uint16_t)(d>>16))*sQ[c*8+5];
            d = v.w; s += bf2f((uint16_t)(d&0xffff))*sQ[c*8+6] + bf2f((uint16_t)(d>>16))*sQ[c*8+7];
        }
        sS[t] = s;
    }
    __syncthreads();
    float lm = -1e30f;
    for (int t = tid; t < TC_; t += 256) lm = fmaxf(lm, sS[t]);
    sR[tid] = lm; __syncthreads();
    for (int o = 128; o > 0; o >>= 1) { if (tid < o) sR[tid] = fmaxf(sR[tid], sR[tid+o]); __syncthreads(); }
    float M = sR[0]; __syncthreads();
    float ls = 0.f;
    for (int t = tid; t < TC_; t += 256) { float e = __expf(sS[t]-M); sS[t] = e; ls += e; }
    sR[tid] = ls; __syncthreads();
    for (int o = 128; o > 0; o >>= 1) { if (tid < o) sR[tid] += sR[tid+o]; __syncthreads(); }
    float inv = 1.f / sR[0]; __syncthreads();
    float la[5] = {0.f,0.f,0.f,0.f,0.f};
    for (int t = tid; t < TC_; t += 256) {
        float p = sS[t] * inv;
        #pragma unroll
        for (int ll = 0; ll < 5; ++ll) la[ll] += p * fcw[ll*TC_ + t];
    }
    float lg[5];
    #pragma unroll
    for (int ll = 0; ll < 5; ++ll) {
        sR[tid] = la[ll]; __syncthreads();
        for (int o = 128; o > 0; o >>= 1) { if (tid < o) sR[tid] += sR[tid+o]; __syncthreads(); }
        lg[ll] = sR[0] + fcb[ll]; __syncthreads();
    }
    if (tid == 0) {
        float m2 = lg[0];
        #pragma unroll
        for (int ll = 1; ll < 5; ++ll) m2 = fmaxf(m2, lg[ll]);
        float se = 0.f;
        #pragma unroll
        for (int ll = 0; ll < 5; ++ll) se += __expf(lg[ll] - m2);
        float lse = __logf(se) + m2;
        #pragma unroll
        for (int ll = 0; ll < 5; ++ll) out[b*5 + ll] = lg[ll] - lse;
    }
}

// ---------------------------------------------------------------------------
extern "C" void kernel_launch(void* const* d_in, const int* in_sizes, int n_in,
                              void* d_out, int out_size, void* d_ws, size_t ws_size,
                              hipStream_t stream)
{
    const int*   content = (const int*)d_in[0];
    const int*   title   = (const int*)d_in[1];
    const float* embed_w = (const float*)d_in[2];
    const float* t_wih_f = (const float*)d_in[3];
    const float* t_whh_f = (const float*)d_in[4];
    const float* t_b_f   = (const float*)d_in[5];
    const float* t_wih_b = (const float*)d_in[6];
    const float* t_b_b   = (const float*)d_in[8];
    const float* c_wih_f = (const float*)d_in[9];
    const float* c_whh_f = (const float*)d_in[10];
    const float* c_b_f   = (const float*)d_in[11];
    const float* c_wih_b = (const float*)d_in[12];
    const float* c_whh_b = (const float*)d_in[13];
    const float* c_b_b   = (const float*)d_in[14];
    const float* att_w   = (const float*)d_in[15];
    const float* fc_w    = (const float*)d_in[16];
    const float* fc_b    = (const float*)d_in[17];
    float* out = (float*)d_out;

    char* ws = (char*)d_ws;
    size_t o = 0;
    auto alloc = [&](size_t sz) { char* p = ws + o; o = (o + sz + 255) & ~(size_t)255; return p; };
    uint16_t* Ac    = (uint16_t*)alloc((size_t)40832*KP_*2);
    uint16_t* At    = (uint16_t*)alloc((size_t)1536*KP_*2);
    uint16_t* BwC   = (uint16_t*)alloc((size_t)NG_*KP_*2);
    uint16_t* BwT   = (uint16_t*)alloc((size_t)NG_*KP_*2);
    float*    biasC = (float*)   alloc((size_t)NG_*4);
    float*    biasT = (float*)   alloc((size_t)NG_*4);
    uint8_t*  w8CF  = (uint8_t*) alloc((size_t)1024*H_);
    uint8_t*  w8CB  = (uint8_t*) alloc((size_t)1024*H_);
    uint8_t*  w8TF  = (uint8_t*) alloc((size_t)1024*H_);
    uint16_t* preC  = (uint16_t*)alloc((size_t)TCP_*262144);
    uint16_t* preT  = (uint16_t*)alloc((size_t)TT_*262144);
    uint16_t* crp   = (uint16_t*)alloc((size_t)B_*TC_*512*2);
    float*    tlp   = (float*)   alloc((size_t)B_*512*4);

    k_pg<<<2304, 256, 0, stream>>>(t_wih_f, t_wih_b, t_whh_f, c_wih_f, c_wih_b,
                                   c_whh_f, c_whh_b, t_b_f, t_b_b, c_b_f, c_b_b,
                                   BwC, BwT, biasC, biasT,
                                   (uint32_t*)w8CF, (uint32_t*)w8CB, (uint32_t*)w8TF,
                                   content, title, embed_w, Ac, At);
    k_gemm<<<dim3(16, 331), 256, 0, stream>>>(Ac, BwC, biasC, preC,
                                              At, BwT, biasT, preT);
    k_rnn<<<16, 1024, 0, stream>>>(preC, preT, w8CF, w8CB, w8TF, crp, tlp);
    k_attn<<<64, 256, 0, stream>>>(crp, tlp, att_w, fc_w, fc_b, out);
}